// Round 7
// baseline (262.339 us; speedup 1.0000x reference)
//
#include <hip/hip_runtime.h>

#define N_NODES 50000
#define N_EDGES 800000
#define N_GRAPHS 64
#define F_IN 6
#define HID 64
#define EMB 128

#define SCAN_B 256
#define NB_SCAN ((N_NODES + SCAN_B - 1) / SCAN_B)   // 196

// ---- init: zero histogram + pool accumulators ----
__global__ void k_init(int* __restrict__ ecnt, float* __restrict__ gsum,
                       float* __restrict__ gcnt) {
    int i = blockIdx.x * blockDim.x + threadIdx.x;
    if (i < N_NODES) ecnt[i] = 0;
    if (i < N_GRAPHS * HID) gsum[i] = 0.0f;
    if (i < N_GRAPHS) gcnt[i] = 0.0f;
}

// ---- in-degree histogram over edge destinations ----
__global__ void k_hist(const int* __restrict__ dst, int* __restrict__ ecnt) {
    int e = blockIdx.x * blockDim.x + threadIdx.x;
    if (e < N_EDGES) atomicAdd(&ecnt[dst[e]], 1);
}

// ---- pass 1: per-block sums of ecnt ----
__global__ void k_sum(const int* __restrict__ ecnt, int* __restrict__ bsum) {
    __shared__ int s[SCAN_B];
    int i = blockIdx.x * SCAN_B + threadIdx.x;
    s[threadIdx.x] = (i < N_NODES) ? ecnt[i] : 0;
    __syncthreads();
    for (int off = SCAN_B / 2; off > 0; off >>= 1) {
        if (threadIdx.x < off) s[threadIdx.x] += s[threadIdx.x + off];
        __syncthreads();
    }
    if (threadIdx.x == 0) bsum[blockIdx.x] = s[0];
}

// ---- pass 2: exclusive scan of the 196 block sums (one small block) ----
__global__ void k_bscan(const int* __restrict__ bsum, int* __restrict__ boff,
                        int* __restrict__ row_start) {
    __shared__ int s[SCAN_B];
    int t = threadIdx.x;
    int v = (t < NB_SCAN) ? bsum[t] : 0;
    s[t] = v;
    __syncthreads();
    for (int off = 1; off < SCAN_B; off <<= 1) {
        int other = (t >= off) ? s[t - off] : 0;
        __syncthreads();
        s[t] += other;
        __syncthreads();
    }
    if (t < NB_SCAN) boff[t] = s[t] - v;       // exclusive
    if (t == 0) row_start[N_NODES] = N_EDGES;  // known total
}

// ---- pass 3: chunk scan + offset; fused dinv and xs = x*dinv; zero pos ----
__global__ void k_scan3(const int* __restrict__ ecnt, const int* __restrict__ boff,
                        const float* __restrict__ x,
                        int* __restrict__ row_start, int* __restrict__ pos,
                        float* __restrict__ dinv, float* __restrict__ xs) {
    __shared__ int s[SCAN_B];
    int t = threadIdx.x;
    int i = blockIdx.x * SCAN_B + t;
    int v = (i < N_NODES) ? ecnt[i] : 0;
    s[t] = v;
    __syncthreads();
    for (int off = 1; off < SCAN_B; off <<= 1) {
        int other = (t >= off) ? s[t - off] : 0;
        __syncthreads();
        s[t] += other;
        __syncthreads();
    }
    if (i < N_NODES) {
        row_start[i] = boff[blockIdx.x] + s[t] - v;   // exclusive prefix
        pos[i] = 0;
        float dv = rsqrtf((float)(v + 1));            // +1 = self-loop
        dinv[i] = dv;
#pragma unroll
        for (int k = 0; k < F_IN; ++k) xs[i * F_IN + k] = x[i * F_IN + k] * dv;
    }
}

// ---- bucket edges by dst: eidx[row_start[d]+p] = src (weight-free CSR) ----
__global__ void k_bucket(const int* __restrict__ src, const int* __restrict__ dst,
                         const int* __restrict__ row_start, int* __restrict__ pos,
                         int* __restrict__ eidx) {
    int e = blockIdx.x * blockDim.x + threadIdx.x;
    if (e >= N_EDGES) return;
    int s = src[e], d = dst[e];
    int p = atomicAdd(&pos[d], 1);
    eidx[row_start[d] + p] = s;
}

// ---- layer-1 aggregation on xs (6 features): xagg = dinv[d]*(sum xs[s] + xs[d]) ----
__global__ void k_gather_x(const float* __restrict__ xs, const int* __restrict__ row_start,
                           const int* __restrict__ eidx, const float* __restrict__ dinv,
                           float* __restrict__ xagg) {
    int node = (blockIdx.x * blockDim.x + threadIdx.x) >> 6;
    int f = threadIdx.x & 63;
    if (node >= N_NODES) return;
    int beg = __builtin_amdgcn_readfirstlane(row_start[node]);
    int end = __builtin_amdgcn_readfirstlane(row_start[node + 1]);
    bool act = (f < F_IN);
    float sum = 0.0f;
    int j = beg;
    for (; j + 8 <= end; j += 8) {
        int s0 = eidx[j+0], s1 = eidx[j+1], s2 = eidx[j+2], s3 = eidx[j+3];
        int s4 = eidx[j+4], s5 = eidx[j+5], s6 = eidx[j+6], s7 = eidx[j+7];
        if (act) {
            float v0 = xs[s0 * F_IN + f], v1 = xs[s1 * F_IN + f];
            float v2 = xs[s2 * F_IN + f], v3 = xs[s3 * F_IN + f];
            float v4 = xs[s4 * F_IN + f], v5 = xs[s5 * F_IN + f];
            float v6 = xs[s6 * F_IN + f], v7 = xs[s7 * F_IN + f];
            sum += ((v0 + v1) + (v2 + v3)) + ((v4 + v5) + (v6 + v7));
        }
    }
    for (; j < end; ++j) {
        int s = eidx[j];
        if (act) sum += xs[s * F_IN + f];
    }
    if (act) {
        sum += xs[node * F_IN + f];
        xagg[node * F_IN + f] = sum * dinv[node];
    }
}

// ---- layer-1 matmul fused with bias+relu: out = relu(xagg @ W + b) ----
__global__ void k_mm_br(const float* __restrict__ xagg, const float* __restrict__ W,
                        const float* __restrict__ b, float* __restrict__ out) {
    __shared__ float sW[F_IN * HID];
    for (int i = threadIdx.x; i < F_IN * HID; i += blockDim.x) sW[i] = W[i];
    __syncthreads();
    int gid = blockIdx.x * blockDim.x + threadIdx.x;
    int node = gid >> 6;
    int f = gid & 63;
    if (node >= N_NODES) return;
    float s = b[f];
#pragma unroll
    for (int k = 0; k < F_IN; ++k) s += xagg[node * F_IN + k] * sW[k * HID + f];
    out[node * HID + f] = fmaxf(s, 0.0f);
}

// ---- h' = (x @ W) * dinv[node] : W col in VGPRs, x bcast via v_readlane ----
__device__ __forceinline__ float bcast(float v, int lane) {
    return __int_as_float(__builtin_amdgcn_readlane(__float_as_int(v), lane));
}

#define MM_BLOCKS 625    // 625 blocks * 4 waves = 2500 waves; 20 nodes/wave
__global__ void k_mm(const float* __restrict__ x, const float* __restrict__ W,
                     const float* __restrict__ dinv, float* __restrict__ h) {
    int f = threadIdx.x & 63;
    float wk[HID];
#pragma unroll
    for (int k = 0; k < HID; ++k) wk[k] = W[k * HID + f];
    int wv = blockIdx.x * (blockDim.x >> 6) + (threadIdx.x >> 6);
    const int nwaves = MM_BLOCKS * 4;
    for (int node = wv; node < N_NODES; node += nwaves) {
        float xv = x[node * HID + f];    // lane f holds x[node][f]
        float dv = dinv[node];
        float a0 = 0.0f, a1 = 0.0f, a2 = 0.0f, a3 = 0.0f;
#pragma unroll
        for (int k = 0; k < HID; k += 4) {
            a0 = fmaf(bcast(xv, k + 0), wk[k + 0], a0);
            a1 = fmaf(bcast(xv, k + 1), wk[k + 1], a1);
            a2 = fmaf(bcast(xv, k + 2), wk[k + 2], a2);
            a3 = fmaf(bcast(xv, k + 3), wk[k + 3], a3);
        }
        h[node * HID + f] = ((a0 + a1) + (a2 + a3)) * dv;
    }
}

// ---- per-node gather: out = relu(dinv[d]*(sum h'[s] + h'[d]) + b) ----
__global__ void k_gather(const float* __restrict__ h, const int* __restrict__ row_start,
                         const int* __restrict__ eidx, const float* __restrict__ dinv,
                         const float* __restrict__ b, float* __restrict__ out) {
    int node = (blockIdx.x * blockDim.x + threadIdx.x) >> 6;
    int f = threadIdx.x & 63;
    if (node >= N_NODES) return;
    int beg = __builtin_amdgcn_readfirstlane(row_start[node]);
    int end = __builtin_amdgcn_readfirstlane(row_start[node + 1]);
    float sum = 0.0f;
    int j = beg;
    for (; j + 8 <= end; j += 8) {
        int s0 = eidx[j+0], s1 = eidx[j+1], s2 = eidx[j+2], s3 = eidx[j+3];
        int s4 = eidx[j+4], s5 = eidx[j+5], s6 = eidx[j+6], s7 = eidx[j+7];
        float v0 = h[s0 * HID + f], v1 = h[s1 * HID + f];
        float v2 = h[s2 * HID + f], v3 = h[s3 * HID + f];
        float v4 = h[s4 * HID + f], v5 = h[s5 * HID + f];
        float v6 = h[s6 * HID + f], v7 = h[s7 * HID + f];
        sum += ((v0 + v1) + (v2 + v3)) + ((v4 + v5) + (v6 + v7));
    }
    for (; j < end; ++j) {
        sum += h[eidx[j] * HID + f];
    }
    sum += h[node * HID + f];                       // self-loop (h' already has dinv[s])
    out[node * HID + f] = fmaxf(fmaf(sum, dinv[node], b[f]), 0.0f);
}

// ---- segment sum for global mean pool (batch sorted; register partials) ----
#define POOL_BLOCKS 200
__global__ void k_pool(const float* __restrict__ x, const int* __restrict__ batch,
                       float* __restrict__ gsum, float* __restrict__ gcnt) {
    const int npb = (N_NODES + POOL_BLOCKS - 1) / POOL_BLOCKS;   // 250
    int start = blockIdx.x * npb;
    int end = start + npb;
    if (end > N_NODES) end = N_NODES;
    int f = threadIdx.x & 63;
    int grp = threadIdx.x >> 6;       // 0..3 (4 waves)
    float sum = 0.0f, cnt = 0.0f;
    int curg = -1;
    for (int node = start + grp; node < end; node += 4) {
        int g = batch[node];
        if (g != curg) {
            if (curg >= 0) {
                atomicAdd(&gsum[curg * HID + f], sum);
                if (f == 0) atomicAdd(&gcnt[curg], cnt);
            }
            curg = g; sum = 0.0f; cnt = 0.0f;
        }
        sum += x[node * HID + f];
        cnt += 1.0f;
    }
    if (curg >= 0) {
        atomicAdd(&gsum[curg * HID + f], sum);
        if (f == 0) atomicAdd(&gcnt[curg], cnt);
    }
}

// ---- final FC: out = relu((gsum/cnt) @ Wfc + bfc) ----
__global__ void k_fc(const float* __restrict__ gsum, const float* __restrict__ gcnt,
                     const float* __restrict__ Wfc, const float* __restrict__ bfc,
                     float* __restrict__ out) {
    int gid = blockIdx.x * blockDim.x + threadIdx.x;   // 64*128 threads
    if (gid >= N_GRAPHS * EMB) return;
    int g = gid >> 7;
    int j = gid & 127;
    float inv = 1.0f / fmaxf(gcnt[g], 1.0f);
    float s = bfc[j];
#pragma unroll 8
    for (int k = 0; k < HID; ++k) s += gsum[g * HID + k] * inv * Wfc[k * EMB + j];
    out[gid] = fmaxf(s, 0.0f);
}

extern "C" void kernel_launch(void* const* d_in, const int* in_sizes, int n_in,
                              void* d_out, int out_size, void* d_ws, size_t ws_size,
                              hipStream_t stream) {
    const float* x    = (const float*)d_in[0];
    const int*   ei   = (const int*)d_in[1];
    const int*   batch= (const int*)d_in[2];
    const float* W1   = (const float*)d_in[3];
    const float* b1   = (const float*)d_in[4];
    const float* W2   = (const float*)d_in[5];
    const float* b2   = (const float*)d_in[6];
    const float* W3   = (const float*)d_in[7];
    const float* b3   = (const float*)d_in[8];
    const float* Wfc  = (const float*)d_in[9];
    const float* bfc  = (const float*)d_in[10];
    float* out = (float*)d_out;

    // workspace layout (4-byte words)
    float* ws        = (float*)d_ws;
    float* dinv      = ws;                                 // 50048
    float* h         = ws + 50048;                         // 3.2M (also xagg in layer 1)
    float* xcur      = h + N_NODES * HID;                  // 3.2M
    float* gsum      = xcur + N_NODES * HID;               // 4096
    float* gcnt      = gsum + N_GRAPHS * HID;              // 64
    float* xs        = gcnt + 64;                          // 300032 (x * dinv)
    int*   ecnt      = (int*)(xs + 300032);                // 50048
    int*   row_start = ecnt + 50048;                       // 50056
    int*   pos       = row_start + 50056;                  // 50048
    int*   bsum      = pos + 50048;                        // 256
    int*   boff      = bsum + 256;                         // 256
    int*   eidx      = boff + 256;                         // 800000 ints
    float* xagg      = h;                                  // [N, F_IN] reuse

    const int* src = ei;                       // edge_index[0]
    const int* dst = ei + N_EDGES;             // edge_index[1]

    const int B = 256;
    const int gN   = (N_NODES + B - 1) / B;
    const int gE   = (N_EDGES + B - 1) / B;
    const int gNF  = (N_NODES * HID + B - 1) / B;

    // CSR build (weight-free: normalization folded into node scaling)
    k_init<<<gN, B, 0, stream>>>(ecnt, gsum, gcnt);
    k_hist<<<gE, B, 0, stream>>>(dst, ecnt);
    k_sum<<<NB_SCAN, SCAN_B, 0, stream>>>(ecnt, bsum);
    k_bscan<<<1, SCAN_B, 0, stream>>>(bsum, boff, row_start);
    k_scan3<<<NB_SCAN, SCAN_B, 0, stream>>>(ecnt, boff, x, row_start, pos, dinv, xs);
    k_bucket<<<gE, B, 0, stream>>>(src, dst, row_start, pos, eidx);

    // layer 1: aggregate-then-transform (X is only 6-wide)
    k_gather_x<<<gNF, B, 0, stream>>>(xs, row_start, eidx, dinv, xagg);
    k_mm_br<<<gNF, B, 0, stream>>>(xagg, W1, b1, xcur);
    // layer 2
    k_mm<<<MM_BLOCKS, B, 0, stream>>>(xcur, W2, dinv, h);
    k_gather<<<gNF, B, 0, stream>>>(h, row_start, eidx, dinv, b2, xcur);
    // layer 3
    k_mm<<<MM_BLOCKS, B, 0, stream>>>(xcur, W3, dinv, h);
    k_gather<<<gNF, B, 0, stream>>>(h, row_start, eidx, dinv, b3, xcur);

    // pool + FC
    k_pool<<<POOL_BLOCKS, B, 0, stream>>>(xcur, batch, gsum, gcnt);
    k_fc<<<(N_GRAPHS * EMB + B - 1) / B, B, 0, stream>>>(gsum, gcnt, Wfc, bfc, out);
}

// Round 8
// 221.274 us; speedup vs baseline: 1.1856x; 1.1856x over previous
//
#include <hip/hip_runtime.h>

#define N_NODES 50000
#define N_EDGES 800000
#define N_GRAPHS 64
#define F_IN 6
#define HID 64
#define EMB 128

#define NBINS 196            // ceil(50000/256) bins of 256 dst nodes
#define EPB 4096             // edges per partition block
#define NCHUNK ((N_EDGES + EPB - 1) / EPB)   // 196
#define EPT (EPB / 256)      // 16 edges per thread

#define SCAN_B 256
#define NB_SCAN ((N_NODES + SCAN_B - 1) / SCAN_B)   // 196

// ---- init: zero bin histogram + pool accumulators ----
__global__ void k_init(int* __restrict__ bin_cnt, float* __restrict__ gsum,
                       float* __restrict__ gcnt) {
    int i = blockIdx.x * blockDim.x + threadIdx.x;
    if (i < NBINS) bin_cnt[i] = 0;
    if (i < N_GRAPHS * HID) gsum[i] = 0.0f;
    if (i < N_GRAPHS) gcnt[i] = 0.0f;
}

// ---- coarse histogram: edges per 256-node dst bin (LDS-aggregated) ----
__global__ void k_binhist(const int* __restrict__ dst, int* __restrict__ bin_cnt) {
    __shared__ int lcnt[NBINS];
    for (int b = threadIdx.x; b < NBINS; b += 256) lcnt[b] = 0;
    __syncthreads();
    int e0 = blockIdx.x * EPB;
#pragma unroll
    for (int t = 0; t < EPT; ++t) {
        int e = e0 + t * 256 + threadIdx.x;
        if (e < N_EDGES) atomicAdd(&lcnt[dst[e] >> 8], 1);
    }
    __syncthreads();
    for (int b = threadIdx.x; b < NBINS; b += 256) {
        int c = lcnt[b];
        if (c) atomicAdd(&bin_cnt[b], c);
    }
}

// ---- exclusive scan of 196 bin counts (1 small block) ----
__global__ void k_binscan(const int* __restrict__ bin_cnt, int* __restrict__ bin_start,
                          int* __restrict__ bin_pos) {
    __shared__ int s[256];
    int t = threadIdx.x;
    int v = (t < NBINS) ? bin_cnt[t] : 0;
    s[t] = v;
    __syncthreads();
    for (int off = 1; off < 256; off <<= 1) {
        int o = (t >= off) ? s[t - off] : 0;
        __syncthreads();
        s[t] += o;
        __syncthreads();
    }
    if (t < NBINS) { int st = s[t] - v; bin_start[t] = st; bin_pos[t] = st; }
    if (t == 0) bin_start[NBINS] = N_EDGES;
}

// ---- coarse partition: LDS-ranked, one range-reservation per (block,bin) ----
// rec = (src << 8) | (dst & 255)   [src < 65536]
__global__ void k_part(const int* __restrict__ src, const int* __restrict__ dst,
                       int* __restrict__ bin_pos, int* __restrict__ rec) {
    __shared__ int lcnt[NBINS];
    __shared__ int lbase[NBINS];
    for (int b = threadIdx.x; b < NBINS; b += 256) lcnt[b] = 0;
    __syncthreads();
    int e0 = blockIdx.x * EPB;
    int myBin[EPT], myRank[EPT], myRec[EPT];
#pragma unroll
    for (int t = 0; t < EPT; ++t) {
        int e = e0 + t * 256 + threadIdx.x;
        myBin[t] = -1;
        if (e < N_EDGES) {
            int d = dst[e];
            int s = src[e];
            int b = d >> 8;
            myBin[t] = b;
            myRec[t] = (s << 8) | (d & 255);
            myRank[t] = atomicAdd(&lcnt[b], 1);     // LDS atomic: rank in (block,bin)
        }
    }
    __syncthreads();
    for (int b = threadIdx.x; b < NBINS; b += 256) {
        int c = lcnt[b];
        lbase[b] = c ? atomicAdd(&bin_pos[b], c) : 0;   // reserve contiguous run
    }
    __syncthreads();
#pragma unroll
    for (int t = 0; t < EPT; ++t)
        if (myBin[t] >= 0) rec[lbase[myBin[t]] + myRank[t]] = myRec[t];
}

// ---- per-bin degree (LDS hist) + dinv + xs = x*dinv, all coalesced ----
__global__ void k_bindeg(const int* __restrict__ rec, const int* __restrict__ bin_start,
                         const float* __restrict__ x, int* __restrict__ deg,
                         float* __restrict__ dinv, float* __restrict__ xs) {
    __shared__ int ldeg[256];
    ldeg[threadIdx.x] = 0;
    __syncthreads();
    int beg = bin_start[blockIdx.x], end = bin_start[blockIdx.x + 1];
    for (int r = beg + threadIdx.x; r < end; r += 256)
        atomicAdd(&ldeg[rec[r] & 255], 1);
    __syncthreads();
    int node = blockIdx.x * 256 + threadIdx.x;
    if (node < N_NODES) {
        int d = ldeg[threadIdx.x];
        deg[node] = d;
        float dv = rsqrtf((float)(d + 1));           // +1 = self-loop
        dinv[node] = dv;
#pragma unroll
        for (int k = 0; k < F_IN; ++k) xs[node * F_IN + k] = x[node * F_IN + k] * dv;
    }
}

// ---- row_start scan over deg: per-block sums ----
__global__ void k_sum(const int* __restrict__ deg, int* __restrict__ bsum) {
    __shared__ int s[SCAN_B];
    int i = blockIdx.x * SCAN_B + threadIdx.x;
    s[threadIdx.x] = (i < N_NODES) ? deg[i] : 0;
    __syncthreads();
    for (int off = SCAN_B / 2; off > 0; off >>= 1) {
        if (threadIdx.x < off) s[threadIdx.x] += s[threadIdx.x + off];
        __syncthreads();
    }
    if (threadIdx.x == 0) bsum[blockIdx.x] = s[0];
}

__global__ void k_bscan(const int* __restrict__ bsum, int* __restrict__ boff,
                        int* __restrict__ row_start) {
    __shared__ int s[SCAN_B];
    int t = threadIdx.x;
    int v = (t < NB_SCAN) ? bsum[t] : 0;
    s[t] = v;
    __syncthreads();
    for (int off = 1; off < SCAN_B; off <<= 1) {
        int other = (t >= off) ? s[t - off] : 0;
        __syncthreads();
        s[t] += other;
        __syncthreads();
    }
    if (t < NB_SCAN) boff[t] = s[t] - v;
    if (t == 0) row_start[N_NODES] = N_EDGES;
}

__global__ void k_scan3(const int* __restrict__ deg, const int* __restrict__ boff,
                        int* __restrict__ row_start) {
    __shared__ int s[SCAN_B];
    int t = threadIdx.x;
    int i = blockIdx.x * SCAN_B + t;
    int v = (i < N_NODES) ? deg[i] : 0;
    s[t] = v;
    __syncthreads();
    for (int off = 1; off < SCAN_B; off <<= 1) {
        int other = (t >= off) ? s[t - off] : 0;
        __syncthreads();
        s[t] += other;
        __syncthreads();
    }
    if (i < N_NODES) row_start[i] = boff[blockIdx.x] + s[t] - v;
}

// ---- fine scatter within bin: CSR window ~16KB stays L2-resident ----
__global__ void k_fine(const int* __restrict__ rec, const int* __restrict__ bin_start,
                       const int* __restrict__ row_start, int* __restrict__ eidx) {
    __shared__ int lpos[256];
    lpos[threadIdx.x] = 0;
    __syncthreads();
    int beg = bin_start[blockIdx.x], end = bin_start[blockIdx.x + 1];
    int base = blockIdx.x * 256;
    for (int r = beg + threadIdx.x; r < end; r += 256) {
        int rc = rec[r];
        int ld = rc & 255;
        int p = atomicAdd(&lpos[ld], 1);
        eidx[row_start[base + ld] + p] = rc >> 8;
    }
}

// ---- layer-1 aggregation on xs (6 features): xagg = dinv[d]*(sum xs[s] + xs[d]) ----
__global__ void k_gather_x(const float* __restrict__ xs, const int* __restrict__ row_start,
                           const int* __restrict__ eidx, const float* __restrict__ dinv,
                           float* __restrict__ xagg) {
    int node = (blockIdx.x * blockDim.x + threadIdx.x) >> 6;
    int f = threadIdx.x & 63;
    if (node >= N_NODES) return;
    int beg = __builtin_amdgcn_readfirstlane(row_start[node]);
    int end = __builtin_amdgcn_readfirstlane(row_start[node + 1]);
    bool act = (f < F_IN);
    float sum = 0.0f;
    int j = beg;
    for (; j + 8 <= end; j += 8) {
        int s0 = eidx[j+0], s1 = eidx[j+1], s2 = eidx[j+2], s3 = eidx[j+3];
        int s4 = eidx[j+4], s5 = eidx[j+5], s6 = eidx[j+6], s7 = eidx[j+7];
        if (act) {
            float v0 = xs[s0 * F_IN + f], v1 = xs[s1 * F_IN + f];
            float v2 = xs[s2 * F_IN + f], v3 = xs[s3 * F_IN + f];
            float v4 = xs[s4 * F_IN + f], v5 = xs[s5 * F_IN + f];
            float v6 = xs[s6 * F_IN + f], v7 = xs[s7 * F_IN + f];
            sum += ((v0 + v1) + (v2 + v3)) + ((v4 + v5) + (v6 + v7));
        }
    }
    for (; j < end; ++j) {
        int s = eidx[j];
        if (act) sum += xs[s * F_IN + f];
    }
    if (act) {
        sum += xs[node * F_IN + f];
        xagg[node * F_IN + f] = sum * dinv[node];
    }
}

// ---- layer-1 matmul fused with bias+relu ----
__global__ void k_mm_br(const float* __restrict__ xagg, const float* __restrict__ W,
                        const float* __restrict__ b, float* __restrict__ out) {
    __shared__ float sW[F_IN * HID];
    for (int i = threadIdx.x; i < F_IN * HID; i += blockDim.x) sW[i] = W[i];
    __syncthreads();
    int gid = blockIdx.x * blockDim.x + threadIdx.x;
    int node = gid >> 6;
    int f = gid & 63;
    if (node >= N_NODES) return;
    float s = b[f];
#pragma unroll
    for (int k = 0; k < F_IN; ++k) s += xagg[node * F_IN + k] * sW[k * HID + f];
    out[node * HID + f] = fmaxf(s, 0.0f);
}

// ---- h' = (x @ W) * dinv : W col in VGPRs, x bcast via v_readlane ----
__device__ __forceinline__ float bcast(float v, int lane) {
    return __int_as_float(__builtin_amdgcn_readlane(__float_as_int(v), lane));
}

#define MM_BLOCKS 625
__global__ void k_mm(const float* __restrict__ x, const float* __restrict__ W,
                     const float* __restrict__ dinv, float* __restrict__ h) {
    int f = threadIdx.x & 63;
    float wk[HID];
#pragma unroll
    for (int k = 0; k < HID; ++k) wk[k] = W[k * HID + f];
    int wv = blockIdx.x * (blockDim.x >> 6) + (threadIdx.x >> 6);
    const int nwaves = MM_BLOCKS * 4;
    for (int node = wv; node < N_NODES; node += nwaves) {
        float xv = x[node * HID + f];
        float dv = dinv[node];
        float a0 = 0.0f, a1 = 0.0f, a2 = 0.0f, a3 = 0.0f;
#pragma unroll
        for (int k = 0; k < HID; k += 4) {
            a0 = fmaf(bcast(xv, k + 0), wk[k + 0], a0);
            a1 = fmaf(bcast(xv, k + 1), wk[k + 1], a1);
            a2 = fmaf(bcast(xv, k + 2), wk[k + 2], a2);
            a3 = fmaf(bcast(xv, k + 3), wk[k + 3], a3);
        }
        h[node * HID + f] = ((a0 + a1) + (a2 + a3)) * dv;
    }
}

// ---- per-node gather: out = relu(dinv[d]*(sum h'[s] + h'[d]) + b) ----
__global__ void k_gather(const float* __restrict__ h, const int* __restrict__ row_start,
                         const int* __restrict__ eidx, const float* __restrict__ dinv,
                         const float* __restrict__ b, float* __restrict__ out) {
    int node = (blockIdx.x * blockDim.x + threadIdx.x) >> 6;
    int f = threadIdx.x & 63;
    if (node >= N_NODES) return;
    int beg = __builtin_amdgcn_readfirstlane(row_start[node]);
    int end = __builtin_amdgcn_readfirstlane(row_start[node + 1]);
    float sum = 0.0f;
    int j = beg;
    for (; j + 8 <= end; j += 8) {
        int s0 = eidx[j+0], s1 = eidx[j+1], s2 = eidx[j+2], s3 = eidx[j+3];
        int s4 = eidx[j+4], s5 = eidx[j+5], s6 = eidx[j+6], s7 = eidx[j+7];
        float v0 = h[s0 * HID + f], v1 = h[s1 * HID + f];
        float v2 = h[s2 * HID + f], v3 = h[s3 * HID + f];
        float v4 = h[s4 * HID + f], v5 = h[s5 * HID + f];
        float v6 = h[s6 * HID + f], v7 = h[s7 * HID + f];
        sum += ((v0 + v1) + (v2 + v3)) + ((v4 + v5) + (v6 + v7));
    }
    for (; j < end; ++j) sum += h[eidx[j] * HID + f];
    sum += h[node * HID + f];
    out[node * HID + f] = fmaxf(fmaf(sum, dinv[node], b[f]), 0.0f);
}

// ---- segment sum for global mean pool (batch sorted; register partials) ----
#define POOL_BLOCKS 200
__global__ void k_pool(const float* __restrict__ x, const int* __restrict__ batch,
                       float* __restrict__ gsum, float* __restrict__ gcnt) {
    const int npb = (N_NODES + POOL_BLOCKS - 1) / POOL_BLOCKS;
    int start = blockIdx.x * npb;
    int end = start + npb;
    if (end > N_NODES) end = N_NODES;
    int f = threadIdx.x & 63;
    int grp = threadIdx.x >> 6;
    float sum = 0.0f, cnt = 0.0f;
    int curg = -1;
    for (int node = start + grp; node < end; node += 4) {
        int g = batch[node];
        if (g != curg) {
            if (curg >= 0) {
                atomicAdd(&gsum[curg * HID + f], sum);
                if (f == 0) atomicAdd(&gcnt[curg], cnt);
            }
            curg = g; sum = 0.0f; cnt = 0.0f;
        }
        sum += x[node * HID + f];
        cnt += 1.0f;
    }
    if (curg >= 0) {
        atomicAdd(&gsum[curg * HID + f], sum);
        if (f == 0) atomicAdd(&gcnt[curg], cnt);
    }
}

// ---- final FC ----
__global__ void k_fc(const float* __restrict__ gsum, const float* __restrict__ gcnt,
                     const float* __restrict__ Wfc, const float* __restrict__ bfc,
                     float* __restrict__ out) {
    int gid = blockIdx.x * blockDim.x + threadIdx.x;
    if (gid >= N_GRAPHS * EMB) return;
    int g = gid >> 7;
    int j = gid & 127;
    float inv = 1.0f / fmaxf(gcnt[g], 1.0f);
    float s = bfc[j];
#pragma unroll 8
    for (int k = 0; k < HID; ++k) s += gsum[g * HID + k] * inv * Wfc[k * EMB + j];
    out[gid] = fmaxf(s, 0.0f);
}

extern "C" void kernel_launch(void* const* d_in, const int* in_sizes, int n_in,
                              void* d_out, int out_size, void* d_ws, size_t ws_size,
                              hipStream_t stream) {
    const float* x    = (const float*)d_in[0];
    const int*   ei   = (const int*)d_in[1];
    const int*   batch= (const int*)d_in[2];
    const float* W1   = (const float*)d_in[3];
    const float* b1   = (const float*)d_in[4];
    const float* W2   = (const float*)d_in[5];
    const float* b2   = (const float*)d_in[6];
    const float* W3   = (const float*)d_in[7];
    const float* b3   = (const float*)d_in[8];
    const float* Wfc  = (const float*)d_in[9];
    const float* bfc  = (const float*)d_in[10];
    float* out = (float*)d_out;

    // workspace layout (4-byte words)
    float* ws        = (float*)d_ws;
    float* dinv      = ws;                                 // 50048
    float* h         = ws + 50048;                         // 3.2M (xagg reuse)
    float* xcur      = h + N_NODES * HID;                  // 3.2M
    float* gsum      = xcur + N_NODES * HID;               // 4096
    float* gcnt      = gsum + N_GRAPHS * HID;              // 64
    float* xs        = gcnt + 64;                          // 300032
    int*   deg       = (int*)(xs + 300032);                // 50048
    int*   row_start = deg + 50048;                        // 50176
    int*   bsum      = row_start + 50176;                  // 256
    int*   boff      = bsum + 256;                         // 256
    int*   bin_cnt   = boff + 256;                         // 256
    int*   bin_start = bin_cnt + 256;                      // 256
    int*   bin_pos   = bin_start + 256;                    // 256
    int*   rec       = bin_pos + 256;                      // 800000
    int*   eidx      = rec + 800000;                       // 800000
    float* xagg      = h;                                  // [N, F_IN] reuse

    const int* src = ei;
    const int* dst = ei + N_EDGES;

    const int B = 256;
    const int gN   = (N_NODES + B - 1) / B;
    const int gNF  = (N_NODES * HID + B - 1) / B;

    // CSR build: coarse partition -> per-bin degree -> row_start -> fine scatter
    k_init<<<gN, B, 0, stream>>>(bin_cnt, gsum, gcnt);
    k_binhist<<<NCHUNK, B, 0, stream>>>(dst, bin_cnt);
    k_binscan<<<1, B, 0, stream>>>(bin_cnt, bin_start, bin_pos);
    k_part<<<NCHUNK, B, 0, stream>>>(src, dst, bin_pos, rec);
    k_bindeg<<<NBINS, B, 0, stream>>>(rec, bin_start, x, deg, dinv, xs);
    k_sum<<<NB_SCAN, SCAN_B, 0, stream>>>(deg, bsum);
    k_bscan<<<1, SCAN_B, 0, stream>>>(bsum, boff, row_start);
    k_scan3<<<NB_SCAN, SCAN_B, 0, stream>>>(deg, boff, row_start);
    k_fine<<<NBINS, B, 0, stream>>>(rec, bin_start, row_start, eidx);

    // layer 1: aggregate-then-transform (X is only 6-wide)
    k_gather_x<<<gNF, B, 0, stream>>>(xs, row_start, eidx, dinv, xagg);
    k_mm_br<<<gNF, B, 0, stream>>>(xagg, W1, b1, xcur);
    // layer 2
    k_mm<<<MM_BLOCKS, B, 0, stream>>>(xcur, W2, dinv, h);
    k_gather<<<gNF, B, 0, stream>>>(h, row_start, eidx, dinv, b2, xcur);
    // layer 3
    k_mm<<<MM_BLOCKS, B, 0, stream>>>(xcur, W3, dinv, h);
    k_gather<<<gNF, B, 0, stream>>>(h, row_start, eidx, dinv, b3, xcur);

    // pool + FC
    k_pool<<<POOL_BLOCKS, B, 0, stream>>>(xcur, batch, gsum, gcnt);
    k_fc<<<(N_GRAPHS * EMB + B - 1) / B, B, 0, stream>>>(gsum, gcnt, Wfc, bfc, out);
}

// Round 9
// 206.719 us; speedup vs baseline: 1.2691x; 1.0704x over previous
//
#include <hip/hip_runtime.h>

#define N_NODES 50000
#define N_EDGES 800000
#define N_GRAPHS 64
#define F_IN 6
#define HID 64
#define EMB 128

#define NBINS 196            // ceil(50000/256) bins of 256 dst nodes
#define EPB 4096             // edges per partition block
#define NCHUNK ((N_EDGES + EPB - 1) / EPB)   // 196
#define EPT (EPB / 256)      // 16 edges per thread

// ---- init: zero bin histogram ----
__global__ void k_init(int* __restrict__ bin_cnt) {
    if (threadIdx.x < NBINS + 4) bin_cnt[threadIdx.x] = 0;
}

// ---- coarse histogram: edges per 256-node dst bin (LDS-aggregated) ----
__global__ void k_binhist(const int* __restrict__ dst, int* __restrict__ bin_cnt) {
    __shared__ int lcnt[NBINS];
    for (int b = threadIdx.x; b < NBINS; b += 256) lcnt[b] = 0;
    __syncthreads();
    int e0 = blockIdx.x * EPB;
#pragma unroll
    for (int t = 0; t < EPT; ++t) {
        int e = e0 + t * 256 + threadIdx.x;
        if (e < N_EDGES) atomicAdd(&lcnt[dst[e] >> 8], 1);
    }
    __syncthreads();
    for (int b = threadIdx.x; b < NBINS; b += 256) {
        int c = lcnt[b];
        if (c) atomicAdd(&bin_cnt[b], c);
    }
}

// ---- scan of 196 bin counts; also zero pool accumulators; sentinels ----
__global__ void k_binscan(const int* __restrict__ bin_cnt, int* __restrict__ bin_start,
                          int* __restrict__ bin_pos, int* __restrict__ row_start,
                          float* __restrict__ gsum, float* __restrict__ gcnt) {
    __shared__ int s[256];
    int t = threadIdx.x;
    int v = (t < NBINS) ? bin_cnt[t] : 0;
    s[t] = v;
    __syncthreads();
    for (int off = 1; off < 256; off <<= 1) {
        int o = (t >= off) ? s[t - off] : 0;
        __syncthreads();
        s[t] += o;
        __syncthreads();
    }
    if (t < NBINS) { int st = s[t] - v; bin_start[t] = st; bin_pos[t] = st; }
    if (t == 0) { bin_start[NBINS] = N_EDGES; row_start[N_NODES] = N_EDGES; }
    for (int i = t; i < N_GRAPHS * HID; i += 256) gsum[i] = 0.0f;
    if (t < N_GRAPHS) gcnt[t] = 0.0f;
}

// ---- coarse partition: LDS-ranked, one range-reservation per (block,bin) ----
// rec = (src << 8) | (dst & 255)   [src < 65536]
__global__ void k_part(const int* __restrict__ src, const int* __restrict__ dst,
                       int* __restrict__ bin_pos, int* __restrict__ rec) {
    __shared__ int lcnt[NBINS];
    __shared__ int lbase[NBINS];
    for (int b = threadIdx.x; b < NBINS; b += 256) lcnt[b] = 0;
    __syncthreads();
    int e0 = blockIdx.x * EPB;
    int myBin[EPT], myRank[EPT], myRec[EPT];
#pragma unroll
    for (int t = 0; t < EPT; ++t) {
        int e = e0 + t * 256 + threadIdx.x;
        myBin[t] = -1;
        if (e < N_EDGES) {
            int d = dst[e];
            int s = src[e];
            int b = d >> 8;
            myBin[t] = b;
            myRec[t] = (s << 8) | (d & 255);
            myRank[t] = atomicAdd(&lcnt[b], 1);
        }
    }
    __syncthreads();
    for (int b = threadIdx.x; b < NBINS; b += 256) {
        int c = lcnt[b];
        lbase[b] = c ? atomicAdd(&bin_pos[b], c) : 0;
    }
    __syncthreads();
#pragma unroll
    for (int t = 0; t < EPT; ++t)
        if (myBin[t] >= 0) rec[lbase[myBin[t]] + myRank[t]] = myRec[t];
}

// ---- per-bin: degree hist + intra-bin scan -> row_start; dinv; xs=x*dinv ----
__global__ void k_bindeg(const int* __restrict__ rec, const int* __restrict__ bin_start,
                         const float* __restrict__ x, int* __restrict__ row_start,
                         float* __restrict__ dinv, float* __restrict__ xs) {
    __shared__ int ldeg[256];
    __shared__ int s[256];
    int t = threadIdx.x;
    ldeg[t] = 0;
    __syncthreads();
    int beg = bin_start[blockIdx.x], end = bin_start[blockIdx.x + 1];
    for (int r = beg + t; r < end; r += 256)
        atomicAdd(&ldeg[rec[r] & 255], 1);
    __syncthreads();
    int v = ldeg[t];
    s[t] = v;
    __syncthreads();
    for (int off = 1; off < 256; off <<= 1) {
        int o = (t >= off) ? s[t - off] : 0;
        __syncthreads();
        s[t] += o;
        __syncthreads();
    }
    int node = blockIdx.x * 256 + t;
    if (node < N_NODES) {
        row_start[node] = beg + s[t] - v;             // bin offset + excl prefix
        float dv = rsqrtf((float)(v + 1));            // +1 = self-loop
        dinv[node] = dv;
#pragma unroll
        for (int k = 0; k < F_IN; ++k) xs[node * F_IN + k] = x[node * F_IN + k] * dv;
    }
}

// ---- fine scatter within bin: CSR window ~16KB stays L2-resident ----
__global__ void k_fine(const int* __restrict__ rec, const int* __restrict__ bin_start,
                       const int* __restrict__ row_start, int* __restrict__ eidx) {
    __shared__ int lpos[256];
    lpos[threadIdx.x] = 0;
    __syncthreads();
    int beg = bin_start[blockIdx.x], end = bin_start[blockIdx.x + 1];
    int base = blockIdx.x * 256;
    for (int r = beg + threadIdx.x; r < end; r += 256) {
        int rc = rec[r];
        int ld = rc & 255;
        int p = atomicAdd(&lpos[ld], 1);
        eidx[row_start[base + ld] + p] = rc >> 8;
    }
}

__device__ __forceinline__ float bcast(float v, int lane) {
    return __int_as_float(__builtin_amdgcn_readlane(__float_as_int(v), lane));
}

// ---- layer 1 fused: agg on xs (6-wide) then relu(xagg@W1+b1) in-register ----
__global__ void k_l1(const float* __restrict__ xs, const int* __restrict__ row_start,
                     const int* __restrict__ eidx, const float* __restrict__ dinv,
                     const float* __restrict__ W1, const float* __restrict__ b1,
                     float* __restrict__ out) {
    __shared__ float sW[F_IN * HID];
    __shared__ float sB[HID];
    for (int i = threadIdx.x; i < F_IN * HID; i += 256) sW[i] = W1[i];
    if (threadIdx.x < HID) sB[threadIdx.x] = b1[threadIdx.x];
    __syncthreads();
    int node = (blockIdx.x * blockDim.x + threadIdx.x) >> 6;
    int f = threadIdx.x & 63;
    if (node >= N_NODES) return;
    int beg = __builtin_amdgcn_readfirstlane(row_start[node]);
    int end = __builtin_amdgcn_readfirstlane(row_start[node + 1]);
    bool act = (f < F_IN);
    float sum = 0.0f;
    int j = beg;
    for (; j + 8 <= end; j += 8) {
        int s0 = eidx[j+0], s1 = eidx[j+1], s2 = eidx[j+2], s3 = eidx[j+3];
        int s4 = eidx[j+4], s5 = eidx[j+5], s6 = eidx[j+6], s7 = eidx[j+7];
        if (act) {
            float v0 = xs[s0 * F_IN + f], v1 = xs[s1 * F_IN + f];
            float v2 = xs[s2 * F_IN + f], v3 = xs[s3 * F_IN + f];
            float v4 = xs[s4 * F_IN + f], v5 = xs[s5 * F_IN + f];
            float v6 = xs[s6 * F_IN + f], v7 = xs[s7 * F_IN + f];
            sum += ((v0 + v1) + (v2 + v3)) + ((v4 + v5) + (v6 + v7));
        }
    }
    for (; j < end; ++j) {
        int s = eidx[j];
        if (act) sum += xs[s * F_IN + f];
    }
    float dv = dinv[node];
    float val = act ? (sum + xs[node * F_IN + f]) * dv : 0.0f;   // xagg in lanes 0..5
    float o = sB[f];
    o = fmaf(bcast(val, 0), sW[0 * HID + f], o);
    o = fmaf(bcast(val, 1), sW[1 * HID + f], o);
    o = fmaf(bcast(val, 2), sW[2 * HID + f], o);
    o = fmaf(bcast(val, 3), sW[3 * HID + f], o);
    o = fmaf(bcast(val, 4), sW[4 * HID + f], o);
    o = fmaf(bcast(val, 5), sW[5 * HID + f], o);
    out[node * HID + f] = fmaxf(o, 0.0f);
}

// ---- h' = (x @ W) * dinv : W col in VGPRs, x bcast via v_readlane ----
#define MM_BLOCKS 625
__global__ void k_mm(const float* __restrict__ x, const float* __restrict__ W,
                     const float* __restrict__ dinv, float* __restrict__ h) {
    int f = threadIdx.x & 63;
    float wk[HID];
#pragma unroll
    for (int k = 0; k < HID; ++k) wk[k] = W[k * HID + f];
    int wv = blockIdx.x * (blockDim.x >> 6) + (threadIdx.x >> 6);
    const int nwaves = MM_BLOCKS * 4;
    for (int node = wv; node < N_NODES; node += nwaves) {
        float xv = x[node * HID + f];
        float dv = dinv[node];
        float a0 = 0.0f, a1 = 0.0f, a2 = 0.0f, a3 = 0.0f;
#pragma unroll
        for (int k = 0; k < HID; k += 4) {
            a0 = fmaf(bcast(xv, k + 0), wk[k + 0], a0);
            a1 = fmaf(bcast(xv, k + 1), wk[k + 1], a1);
            a2 = fmaf(bcast(xv, k + 2), wk[k + 2], a2);
            a3 = fmaf(bcast(xv, k + 3), wk[k + 3], a3);
        }
        h[node * HID + f] = ((a0 + a1) + (a2 + a3)) * dv;
    }
}

// ---- per-node gather: out = relu(dinv[d]*(sum h'[s] + h'[d]) + b) ----
__global__ void k_gather(const float* __restrict__ h, const int* __restrict__ row_start,
                         const int* __restrict__ eidx, const float* __restrict__ dinv,
                         const float* __restrict__ b, float* __restrict__ out) {
    int node = (blockIdx.x * blockDim.x + threadIdx.x) >> 6;
    int f = threadIdx.x & 63;
    if (node >= N_NODES) return;
    int beg = __builtin_amdgcn_readfirstlane(row_start[node]);
    int end = __builtin_amdgcn_readfirstlane(row_start[node + 1]);
    float sum = 0.0f;
    int j = beg;
    for (; j + 8 <= end; j += 8) {
        int s0 = eidx[j+0], s1 = eidx[j+1], s2 = eidx[j+2], s3 = eidx[j+3];
        int s4 = eidx[j+4], s5 = eidx[j+5], s6 = eidx[j+6], s7 = eidx[j+7];
        float v0 = h[s0 * HID + f], v1 = h[s1 * HID + f];
        float v2 = h[s2 * HID + f], v3 = h[s3 * HID + f];
        float v4 = h[s4 * HID + f], v5 = h[s5 * HID + f];
        float v6 = h[s6 * HID + f], v7 = h[s7 * HID + f];
        sum += ((v0 + v1) + (v2 + v3)) + ((v4 + v5) + (v6 + v7));
    }
    if (j + 4 <= end) {
        int s0 = eidx[j+0], s1 = eidx[j+1], s2 = eidx[j+2], s3 = eidx[j+3];
        float v0 = h[s0 * HID + f], v1 = h[s1 * HID + f];
        float v2 = h[s2 * HID + f], v3 = h[s3 * HID + f];
        sum += ((v0 + v1) + (v2 + v3));
        j += 4;
    }
    for (; j < end; ++j) sum += h[eidx[j] * HID + f];
    sum += h[node * HID + f];
    out[node * HID + f] = fmaxf(fmaf(sum, dinv[node], b[f]), 0.0f);
}

// ---- segment sum for global mean pool (batch sorted; register partials) ----
#define POOL_BLOCKS 200
__global__ void k_pool(const float* __restrict__ x, const int* __restrict__ batch,
                       float* __restrict__ gsum, float* __restrict__ gcnt) {
    const int npb = (N_NODES + POOL_BLOCKS - 1) / POOL_BLOCKS;
    int start = blockIdx.x * npb;
    int end = start + npb;
    if (end > N_NODES) end = N_NODES;
    int f = threadIdx.x & 63;
    int grp = threadIdx.x >> 6;
    float sum = 0.0f, cnt = 0.0f;
    int curg = -1;
    for (int node = start + grp; node < end; node += 4) {
        int g = batch[node];
        if (g != curg) {
            if (curg >= 0) {
                atomicAdd(&gsum[curg * HID + f], sum);
                if (f == 0) atomicAdd(&gcnt[curg], cnt);
            }
            curg = g; sum = 0.0f; cnt = 0.0f;
        }
        sum += x[node * HID + f];
        cnt += 1.0f;
    }
    if (curg >= 0) {
        atomicAdd(&gsum[curg * HID + f], sum);
        if (f == 0) atomicAdd(&gcnt[curg], cnt);
    }
}

// ---- final FC ----
__global__ void k_fc(const float* __restrict__ gsum, const float* __restrict__ gcnt,
                     const float* __restrict__ Wfc, const float* __restrict__ bfc,
                     float* __restrict__ out) {
    int gid = blockIdx.x * blockDim.x + threadIdx.x;
    if (gid >= N_GRAPHS * EMB) return;
    int g = gid >> 7;
    int j = gid & 127;
    float inv = 1.0f / fmaxf(gcnt[g], 1.0f);
    float s = bfc[j];
#pragma unroll 8
    for (int k = 0; k < HID; ++k) s += gsum[g * HID + k] * inv * Wfc[k * EMB + j];
    out[gid] = fmaxf(s, 0.0f);
}

extern "C" void kernel_launch(void* const* d_in, const int* in_sizes, int n_in,
                              void* d_out, int out_size, void* d_ws, size_t ws_size,
                              hipStream_t stream) {
    const float* x    = (const float*)d_in[0];
    const int*   ei   = (const int*)d_in[1];
    const int*   batch= (const int*)d_in[2];
    const float* W1   = (const float*)d_in[3];
    const float* b1   = (const float*)d_in[4];
    const float* W2   = (const float*)d_in[5];
    const float* b2   = (const float*)d_in[6];
    const float* W3   = (const float*)d_in[7];
    const float* b3   = (const float*)d_in[8];
    const float* Wfc  = (const float*)d_in[9];
    const float* bfc  = (const float*)d_in[10];
    float* out = (float*)d_out;

    // workspace layout (4-byte words)
    float* ws        = (float*)d_ws;
    float* dinv      = ws;                                 // 50048
    float* h         = ws + 50048;                         // 3.2M
    float* xcur      = h + N_NODES * HID;                  // 3.2M
    float* gsum      = xcur + N_NODES * HID;               // 4096
    float* gcnt      = gsum + N_GRAPHS * HID;              // 64
    float* xs        = gcnt + 64;                          // 300032
    int*   row_start = (int*)(xs + 300032);                // 50176
    int*   bin_cnt   = row_start + 50176;                  // 256
    int*   bin_start = bin_cnt + 256;                      // 256
    int*   bin_pos   = bin_start + 256;                    // 256
    int*   rec       = bin_pos + 256;                      // 800000
    int*   eidx      = rec + 800000;                       // 800000

    const int* src = ei;
    const int* dst = ei + N_EDGES;

    const int B = 256;
    const int gNF = (N_NODES * HID + B - 1) / B;

    // CSR build
    k_init<<<1, B, 0, stream>>>(bin_cnt);
    k_binhist<<<NCHUNK, B, 0, stream>>>(dst, bin_cnt);
    k_binscan<<<1, B, 0, stream>>>(bin_cnt, bin_start, bin_pos, row_start, gsum, gcnt);
    k_part<<<NCHUNK, B, 0, stream>>>(src, dst, bin_pos, rec);
    k_bindeg<<<NBINS, B, 0, stream>>>(rec, bin_start, x, row_start, dinv, xs);
    k_fine<<<NBINS, B, 0, stream>>>(rec, bin_start, row_start, eidx);

    // layer 1 (fused aggregate + transform)
    k_l1<<<gNF, B, 0, stream>>>(xs, row_start, eidx, dinv, W1, b1, xcur);
    // layer 2
    k_mm<<<MM_BLOCKS, B, 0, stream>>>(xcur, W2, dinv, h);
    k_gather<<<gNF, B, 0, stream>>>(h, row_start, eidx, dinv, b2, xcur);
    // layer 3
    k_mm<<<MM_BLOCKS, B, 0, stream>>>(xcur, W3, dinv, h);
    k_gather<<<gNF, B, 0, stream>>>(h, row_start, eidx, dinv, b3, xcur);

    // pool + FC
    k_pool<<<POOL_BLOCKS, B, 0, stream>>>(xcur, batch, gsum, gcnt);
    k_fc<<<(N_GRAPHS * EMB + B - 1) / B, B, 0, stream>>>(gsum, gcnt, Wfc, bfc, out);
}

// Round 10
// 178.783 us; speedup vs baseline: 1.4674x; 1.1563x over previous
//
#include <hip/hip_runtime.h>

#define N_NODES 50000
#define N_EDGES 800000
#define N_GRAPHS 64
#define F_IN 6
#define HID 64
#define EMB 128

#define NBINS 196            // ceil(50000/256) bins of 256 dst nodes
#define EPB 4096             // edges per partition block
#define NCHUNK ((N_EDGES + EPB - 1) / EPB)   // 196
#define EPT (EPB / 256)      // 16 edges per thread

// ---- init: zero bin histogram ----
__global__ void k_init(int* __restrict__ bin_cnt) {
    if (threadIdx.x < NBINS + 4) bin_cnt[threadIdx.x] = 0;
}

// ---- coarse histogram: edges per 256-node dst bin (LDS-aggregated) ----
__global__ void k_binhist(const int* __restrict__ dst, int* __restrict__ bin_cnt) {
    __shared__ int lcnt[NBINS];
    for (int b = threadIdx.x; b < NBINS; b += 256) lcnt[b] = 0;
    __syncthreads();
    int e0 = blockIdx.x * EPB;
#pragma unroll
    for (int t = 0; t < EPT; ++t) {
        int e = e0 + t * 256 + threadIdx.x;
        if (e < N_EDGES) atomicAdd(&lcnt[dst[e] >> 8], 1);
    }
    __syncthreads();
    for (int b = threadIdx.x; b < NBINS; b += 256) {
        int c = lcnt[b];
        if (c) atomicAdd(&bin_cnt[b], c);
    }
}

// ---- scan of 196 bin counts; also zero pool accumulators; sentinels ----
__global__ void k_binscan(const int* __restrict__ bin_cnt, int* __restrict__ bin_start,
                          int* __restrict__ bin_pos, int* __restrict__ row_start,
                          float* __restrict__ gsum, float* __restrict__ gcnt) {
    __shared__ int s[256];
    int t = threadIdx.x;
    int v = (t < NBINS) ? bin_cnt[t] : 0;
    s[t] = v;
    __syncthreads();
    for (int off = 1; off < 256; off <<= 1) {
        int o = (t >= off) ? s[t - off] : 0;
        __syncthreads();
        s[t] += o;
        __syncthreads();
    }
    if (t < NBINS) { int st = s[t] - v; bin_start[t] = st; bin_pos[t] = st; }
    if (t == 0) { bin_start[NBINS] = N_EDGES; row_start[N_NODES] = N_EDGES; }
    for (int i = t; i < N_GRAPHS * HID; i += 256) gsum[i] = 0.0f;
    if (t < N_GRAPHS) gcnt[t] = 0.0f;
}

// ---- coarse partition: LDS-ranked, one range-reservation per (block,bin) ----
// rec = (src << 8) | (dst & 255)   [src < 65536]
__global__ void k_part(const int* __restrict__ src, const int* __restrict__ dst,
                       int* __restrict__ bin_pos, int* __restrict__ rec) {
    __shared__ int lcnt[NBINS];
    __shared__ int lbase[NBINS];
    for (int b = threadIdx.x; b < NBINS; b += 256) lcnt[b] = 0;
    __syncthreads();
    int e0 = blockIdx.x * EPB;
    int myBin[EPT], myRank[EPT], myRec[EPT];
#pragma unroll
    for (int t = 0; t < EPT; ++t) {
        int e = e0 + t * 256 + threadIdx.x;
        myBin[t] = -1;
        if (e < N_EDGES) {
            int d = dst[e];
            int s = src[e];
            int b = d >> 8;
            myBin[t] = b;
            myRec[t] = (s << 8) | (d & 255);
            myRank[t] = atomicAdd(&lcnt[b], 1);
        }
    }
    __syncthreads();
    for (int b = threadIdx.x; b < NBINS; b += 256) {
        int c = lcnt[b];
        lbase[b] = c ? atomicAdd(&bin_pos[b], c) : 0;
    }
    __syncthreads();
#pragma unroll
    for (int t = 0; t < EPT; ++t)
        if (myBin[t] >= 0) rec[lbase[myBin[t]] + myRank[t]] = myRec[t];
}

// ---- per-bin: degree hist + intra-bin scan -> row_start; dinv; xs=x*dinv ----
__global__ void k_bindeg(const int* __restrict__ rec, const int* __restrict__ bin_start,
                         const float* __restrict__ x, int* __restrict__ row_start,
                         float* __restrict__ dinv, float* __restrict__ xs) {
    __shared__ int ldeg[256];
    __shared__ int s[256];
    int t = threadIdx.x;
    ldeg[t] = 0;
    __syncthreads();
    int beg = bin_start[blockIdx.x], end = bin_start[blockIdx.x + 1];
    for (int r = beg + t; r < end; r += 256)
        atomicAdd(&ldeg[rec[r] & 255], 1);
    __syncthreads();
    int v = ldeg[t];
    s[t] = v;
    __syncthreads();
    for (int off = 1; off < 256; off <<= 1) {
        int o = (t >= off) ? s[t - off] : 0;
        __syncthreads();
        s[t] += o;
        __syncthreads();
    }
    int node = blockIdx.x * 256 + t;
    if (node < N_NODES) {
        row_start[node] = beg + s[t] - v;             // bin offset + excl prefix
        float dv = rsqrtf((float)(v + 1));            // +1 = self-loop
        dinv[node] = dv;
#pragma unroll
        for (int k = 0; k < F_IN; ++k) xs[node * F_IN + k] = x[node * F_IN + k] * dv;
    }
}

// ---- fine scatter within bin: CSR window ~16KB stays L2-resident ----
__global__ void k_fine(const int* __restrict__ rec, const int* __restrict__ bin_start,
                       const int* __restrict__ row_start, int* __restrict__ eidx) {
    __shared__ int lpos[256];
    lpos[threadIdx.x] = 0;
    __syncthreads();
    int beg = bin_start[blockIdx.x], end = bin_start[blockIdx.x + 1];
    int base = blockIdx.x * 256;
    for (int r = beg + threadIdx.x; r < end; r += 256) {
        int rc = rec[r];
        int ld = rc & 255;
        int p = atomicAdd(&lpos[ld], 1);
        eidx[row_start[base + ld] + p] = rc >> 8;
    }
}

__device__ __forceinline__ float bcast(float v, int lane) {
    return __int_as_float(__builtin_amdgcn_readlane(__float_as_int(v), lane));
}

#define PB 1280   // persistent blocks for fused layer kernels

// ---- fused layer1+mm2: agg(xs) -> relu(@W1+b1) -> h2' = (out@W2)*dinv ----
__global__ void k_l1mm(const float* __restrict__ xs, const int* __restrict__ row_start,
                       const int* __restrict__ eidx, const float* __restrict__ dinv,
                       const float* __restrict__ W1, const float* __restrict__ b1,
                       const float* __restrict__ W2, float* __restrict__ hout) {
    __shared__ float sW[F_IN * HID];
    __shared__ float sB[HID];
    for (int i = threadIdx.x; i < F_IN * HID; i += 256) sW[i] = W1[i];
    if (threadIdx.x < HID) sB[threadIdx.x] = b1[threadIdx.x];
    __syncthreads();
    int f = threadIdx.x & 63;
    float wk[HID];                       // W2 column f, loaded once per wave
#pragma unroll
    for (int k = 0; k < HID; ++k) wk[k] = W2[k * HID + f];
    bool act = (f < F_IN);
    int wv = blockIdx.x * 4 + (threadIdx.x >> 6);
    for (int node = wv; node < N_NODES; node += PB * 4) {
        int beg = __builtin_amdgcn_readfirstlane(row_start[node]);
        int end = __builtin_amdgcn_readfirstlane(row_start[node + 1]);
        float sum = 0.0f;
        int j = beg;
        for (; j + 8 <= end; j += 8) {
            int s0 = eidx[j+0], s1 = eidx[j+1], s2 = eidx[j+2], s3 = eidx[j+3];
            int s4 = eidx[j+4], s5 = eidx[j+5], s6 = eidx[j+6], s7 = eidx[j+7];
            if (act) {
                float v0 = xs[s0 * F_IN + f], v1 = xs[s1 * F_IN + f];
                float v2 = xs[s2 * F_IN + f], v3 = xs[s3 * F_IN + f];
                float v4 = xs[s4 * F_IN + f], v5 = xs[s5 * F_IN + f];
                float v6 = xs[s6 * F_IN + f], v7 = xs[s7 * F_IN + f];
                sum += ((v0 + v1) + (v2 + v3)) + ((v4 + v5) + (v6 + v7));
            }
        }
        for (; j < end; ++j) {
            int s = eidx[j];
            if (act) sum += xs[s * F_IN + f];
        }
        float dv = dinv[node];
        float val = act ? (sum + xs[node * F_IN + f]) * dv : 0.0f;
        float o = sB[f];
        o = fmaf(bcast(val, 0), sW[0 * HID + f], o);
        o = fmaf(bcast(val, 1), sW[1 * HID + f], o);
        o = fmaf(bcast(val, 2), sW[2 * HID + f], o);
        o = fmaf(bcast(val, 3), sW[3 * HID + f], o);
        o = fmaf(bcast(val, 4), sW[4 * HID + f], o);
        o = fmaf(bcast(val, 5), sW[5 * HID + f], o);
        o = fmaxf(o, 0.0f);              // layer-1 output, lane f
        // mm2 epilogue: h2'[f] = (sum_k o_k * W2[k][f]) * dv
        float a0 = 0.0f, a1 = 0.0f, a2 = 0.0f, a3 = 0.0f;
#pragma unroll
        for (int k = 0; k < HID; k += 4) {
            a0 = fmaf(bcast(o, k + 0), wk[k + 0], a0);
            a1 = fmaf(bcast(o, k + 1), wk[k + 1], a1);
            a2 = fmaf(bcast(o, k + 2), wk[k + 2], a2);
            a3 = fmaf(bcast(o, k + 3), wk[k + 3], a3);
        }
        hout[node * HID + f] = ((a0 + a1) + (a2 + a3)) * dv;
    }
}

// ---- fused gather+mm3: agg(h2') -> relu(+b2) -> h3' = (out@W3)*dinv ----
__global__ void k_gmm(const float* __restrict__ h, const int* __restrict__ row_start,
                      const int* __restrict__ eidx, const float* __restrict__ dinv,
                      const float* __restrict__ b2, const float* __restrict__ W3,
                      float* __restrict__ hout) {
    int f = threadIdx.x & 63;
    float wk[HID];                       // W3 column f
#pragma unroll
    for (int k = 0; k < HID; ++k) wk[k] = W3[k * HID + f];
    float bv = b2[f];
    int wv = blockIdx.x * 4 + (threadIdx.x >> 6);
    for (int node = wv; node < N_NODES; node += PB * 4) {
        int beg = __builtin_amdgcn_readfirstlane(row_start[node]);
        int end = __builtin_amdgcn_readfirstlane(row_start[node + 1]);
        float sum = 0.0f;
        int j = beg;
        for (; j + 8 <= end; j += 8) {
            int s0 = eidx[j+0], s1 = eidx[j+1], s2 = eidx[j+2], s3 = eidx[j+3];
            int s4 = eidx[j+4], s5 = eidx[j+5], s6 = eidx[j+6], s7 = eidx[j+7];
            float v0 = h[s0 * HID + f], v1 = h[s1 * HID + f];
            float v2 = h[s2 * HID + f], v3 = h[s3 * HID + f];
            float v4 = h[s4 * HID + f], v5 = h[s5 * HID + f];
            float v6 = h[s6 * HID + f], v7 = h[s7 * HID + f];
            sum += ((v0 + v1) + (v2 + v3)) + ((v4 + v5) + (v6 + v7));
        }
        if (j + 4 <= end) {
            int s0 = eidx[j+0], s1 = eidx[j+1], s2 = eidx[j+2], s3 = eidx[j+3];
            float v0 = h[s0 * HID + f], v1 = h[s1 * HID + f];
            float v2 = h[s2 * HID + f], v3 = h[s3 * HID + f];
            sum += ((v0 + v1) + (v2 + v3));
            j += 4;
        }
        for (; j < end; ++j) sum += h[eidx[j] * HID + f];
        sum += h[node * HID + f];
        float dv = dinv[node];
        float o = fmaxf(fmaf(sum, dv, bv), 0.0f);    // layer-2 output, lane f
        // mm3 epilogue
        float a0 = 0.0f, a1 = 0.0f, a2 = 0.0f, a3 = 0.0f;
#pragma unroll
        for (int k = 0; k < HID; k += 4) {
            a0 = fmaf(bcast(o, k + 0), wk[k + 0], a0);
            a1 = fmaf(bcast(o, k + 1), wk[k + 1], a1);
            a2 = fmaf(bcast(o, k + 2), wk[k + 2], a2);
            a3 = fmaf(bcast(o, k + 3), wk[k + 3], a3);
        }
        hout[node * HID + f] = ((a0 + a1) + (a2 + a3)) * dv;
    }
}

// ---- final per-node gather: out = relu(dinv*(sum h3'[s] + h3'[d]) + b3) ----
__global__ void k_gather(const float* __restrict__ h, const int* __restrict__ row_start,
                         const int* __restrict__ eidx, const float* __restrict__ dinv,
                         const float* __restrict__ b, float* __restrict__ out) {
    int node = (blockIdx.x * blockDim.x + threadIdx.x) >> 6;
    int f = threadIdx.x & 63;
    if (node >= N_NODES) return;
    int beg = __builtin_amdgcn_readfirstlane(row_start[node]);
    int end = __builtin_amdgcn_readfirstlane(row_start[node + 1]);
    float sum = 0.0f;
    int j = beg;
    for (; j + 8 <= end; j += 8) {
        int s0 = eidx[j+0], s1 = eidx[j+1], s2 = eidx[j+2], s3 = eidx[j+3];
        int s4 = eidx[j+4], s5 = eidx[j+5], s6 = eidx[j+6], s7 = eidx[j+7];
        float v0 = h[s0 * HID + f], v1 = h[s1 * HID + f];
        float v2 = h[s2 * HID + f], v3 = h[s3 * HID + f];
        float v4 = h[s4 * HID + f], v5 = h[s5 * HID + f];
        float v6 = h[s6 * HID + f], v7 = h[s7 * HID + f];
        sum += ((v0 + v1) + (v2 + v3)) + ((v4 + v5) + (v6 + v7));
    }
    if (j + 4 <= end) {
        int s0 = eidx[j+0], s1 = eidx[j+1], s2 = eidx[j+2], s3 = eidx[j+3];
        float v0 = h[s0 * HID + f], v1 = h[s1 * HID + f];
        float v2 = h[s2 * HID + f], v3 = h[s3 * HID + f];
        sum += ((v0 + v1) + (v2 + v3));
        j += 4;
    }
    for (; j < end; ++j) sum += h[eidx[j] * HID + f];
    sum += h[node * HID + f];
    out[node * HID + f] = fmaxf(fmaf(sum, dinv[node], b[f]), 0.0f);
}

// ---- segment sum for global mean pool (batch sorted; register partials) ----
#define POOL_BLOCKS 200
__global__ void k_pool(const float* __restrict__ x, const int* __restrict__ batch,
                       float* __restrict__ gsum, float* __restrict__ gcnt) {
    const int npb = (N_NODES + POOL_BLOCKS - 1) / POOL_BLOCKS;
    int start = blockIdx.x * npb;
    int end = start + npb;
    if (end > N_NODES) end = N_NODES;
    int f = threadIdx.x & 63;
    int grp = threadIdx.x >> 6;
    float sum = 0.0f, cnt = 0.0f;
    int curg = -1;
    for (int node = start + grp; node < end; node += 4) {
        int g = batch[node];
        if (g != curg) {
            if (curg >= 0) {
                atomicAdd(&gsum[curg * HID + f], sum);
                if (f == 0) atomicAdd(&gcnt[curg], cnt);
            }
            curg = g; sum = 0.0f; cnt = 0.0f;
        }
        sum += x[node * HID + f];
        cnt += 1.0f;
    }
    if (curg >= 0) {
        atomicAdd(&gsum[curg * HID + f], sum);
        if (f == 0) atomicAdd(&gcnt[curg], cnt);
    }
}

// ---- final FC ----
__global__ void k_fc(const float* __restrict__ gsum, const float* __restrict__ gcnt,
                     const float* __restrict__ Wfc, const float* __restrict__ bfc,
                     float* __restrict__ out) {
    int gid = blockIdx.x * blockDim.x + threadIdx.x;
    if (gid >= N_GRAPHS * EMB) return;
    int g = gid >> 7;
    int j = gid & 127;
    float inv = 1.0f / fmaxf(gcnt[g], 1.0f);
    float s = bfc[j];
#pragma unroll 8
    for (int k = 0; k < HID; ++k) s += gsum[g * HID + k] * inv * Wfc[k * EMB + j];
    out[gid] = fmaxf(s, 0.0f);
}

extern "C" void kernel_launch(void* const* d_in, const int* in_sizes, int n_in,
                              void* d_out, int out_size, void* d_ws, size_t ws_size,
                              hipStream_t stream) {
    const float* x    = (const float*)d_in[0];
    const int*   ei   = (const int*)d_in[1];
    const int*   batch= (const int*)d_in[2];
    const float* W1   = (const float*)d_in[3];
    const float* b1   = (const float*)d_in[4];
    const float* W2   = (const float*)d_in[5];
    const float* b2   = (const float*)d_in[6];
    const float* W3   = (const float*)d_in[7];
    const float* b3   = (const float*)d_in[8];
    const float* Wfc  = (const float*)d_in[9];
    const float* bfc  = (const float*)d_in[10];
    float* out = (float*)d_out;

    // workspace layout (4-byte words)
    float* ws        = (float*)d_ws;
    float* dinv      = ws;                                 // 50048
    float* h         = ws + 50048;                         // 3.2M  (h2' / out3)
    float* xcur      = h + N_NODES * HID;                  // 3.2M  (h3')
    float* gsum      = xcur + N_NODES * HID;               // 4096
    float* gcnt      = gsum + N_GRAPHS * HID;              // 64
    float* xs        = gcnt + 64;                          // 300032
    int*   row_start = (int*)(xs + 300032);                // 50176
    int*   bin_cnt   = row_start + 50176;                  // 256
    int*   bin_start = bin_cnt + 256;                      // 256
    int*   bin_pos   = bin_start + 256;                    // 256
    int*   rec       = bin_pos + 256;                      // 800000
    int*   eidx      = rec + 800000;                       // 800000

    const int* src = ei;
    const int* dst = ei + N_EDGES;

    const int B = 256;
    const int gNF = (N_NODES * HID + B - 1) / B;

    // CSR build
    k_init<<<1, B, 0, stream>>>(bin_cnt);
    k_binhist<<<NCHUNK, B, 0, stream>>>(dst, bin_cnt);
    k_binscan<<<1, B, 0, stream>>>(bin_cnt, bin_start, bin_pos, row_start, gsum, gcnt);
    k_part<<<NCHUNK, B, 0, stream>>>(src, dst, bin_pos, rec);
    k_bindeg<<<NBINS, B, 0, stream>>>(rec, bin_start, x, row_start, dinv, xs);
    k_fine<<<NBINS, B, 0, stream>>>(rec, bin_start, row_start, eidx);

    // layer 1 + mm2 fused -> h2'
    k_l1mm<<<PB, B, 0, stream>>>(xs, row_start, eidx, dinv, W1, b1, W2, h);
    // layer 2 gather + mm3 fused -> h3'
    k_gmm<<<PB, B, 0, stream>>>(h, row_start, eidx, dinv, b2, W3, xcur);
    // layer 3 gather -> out3
    k_gather<<<gNF, B, 0, stream>>>(xcur, row_start, eidx, dinv, b3, h);

    // pool + FC
    k_pool<<<POOL_BLOCKS, B, 0, stream>>>(h, batch, gsum, gcnt);
    k_fc<<<(N_GRAPHS * EMB + B - 1) / B, B, 0, stream>>>(gsum, gcnt, Wfc, bfc, out);
}